// Round 7
// baseline (99.997 us; speedup 1.0000x reference)
//
#include <hip/hip_runtime.h>
#include <math.h>

#define R_N    8192
#define HALF_R 4096
#define K_TOP  32
#define CAND   512
// 10*log2(e): exp(10*x) = exp2(C1*x)
#define C1     14.426950408889634f
#define NEG_BIG (-3.0e38f)
#define MAGIC  0x5CA1AB1Eu
#define REC_STRIDE 96                      // floats per half-row record
#define FLAG_FOFF  32768                   // float offset of flag array (128 KB)

__device__ __forceinline__ float fast_exp2(float x) {
#if __has_builtin(__builtin_amdgcn_exp2f)
    return __builtin_amdgcn_exp2f(x);
#else
    return exp2f(x);
#endif
}

// ---- bitonic helpers (l = tid & 31 unless noted) ----
__device__ __forceinline__ float merge_asc32(float v, int l) {
#pragma unroll
    for (int j = 16; j > 0; j >>= 1) {
        float pv = __shfl_xor(v, j, 64);
        v = ((l & j) == 0) ? fminf(v, pv) : fmaxf(v, pv);
    }
    return v;
}

__device__ __forceinline__ float sort32_asc(float v, int l) {
#pragma unroll
    for (int k = 2; k <= 32; k <<= 1) {
#pragma unroll
        for (int j = k >> 1; j > 0; j >>= 1) {
            float pv = __shfl_xor(v, j, 64);
            bool keep_min = (((l & k) == 0) == ((l & j) == 0));
            v = keep_min ? fminf(v, pv) : fmaxf(v, pv);
        }
    }
    return v;
}

__device__ __forceinline__ float sort64_asc(float v, int lane) {
#pragma unroll
    for (int k = 2; k <= 64; k <<= 1) {
#pragma unroll
        for (int j = k >> 1; j > 0; j >>= 1) {
            float pv = __shfl_xor(v, j, 64);
            bool keep_min = (((lane & k) == 0) == ((lane & j) == 0));
            v = keep_min ? fminf(v, pv) : fmaxf(v, pv);
        }
    }
    return v;
}

// a, b ascending 32-lists: ascending top-32 of union
__device__ __forceinline__ float merge_top32(float a, float b, int l) {
    float rev = __shfl_xor(b, 31, 64);
    return merge_asc32(fmaxf(a, rev), l);
}

// One block per (row, half). Odd block posts its record to ws and exits;
// even block spins on the flag, combines, writes both outputs.
extern "C" __global__ void __launch_bounds__(512)
k_half(const float* __restrict__ scores, const int* __restrict__ rc,
       float* __restrict__ out, float* __restrict__ ws, int B) {
    __shared__ float    cand[CAND];
    __shared__ float    topbuf[16 * 32];
    __shared__ float    twbuf[8];
    __shared__ float    mytop[K_TOP];
    __shared__ float    yk_lds[K_TOP];
    __shared__ float    pbuf[8 * 2];
    __shared__ float    dsS[62], dsC[62];   // [0..30] own direct, [31..61] partner
    __shared__ unsigned cnt, dcnt;

    const int blk  = blockIdx.x;
    const int row  = blk >> 1;
    const int half = blk & 1;
    const int tid  = threadIdx.x;
    const int lane = tid & 63;
    const int l    = tid & 31;
    const int h    = tid >> 5;              // 32-group id (0..15)
    const int wv   = tid >> 6;              // wave id (0..7)

    cand[tid] = NEG_BIG;                    // CAND == blockDim
    if (tid == 0) { cnt = 0; dcnt = 0; }
    if (tid < 62) { dsS[tid] = NEG_BIG; dsC[tid] = 0.f; }

    // ---- load 8 scores + 8 classes per thread (half a row) ----
    const float4* s4 = (const float4*)(scores + (size_t)row * R_N + half * HALF_R);
    const int4*   c4 = (const int4*)(rc + half * HALF_R);
    float4 sa = s4[tid], sb = s4[tid + 512];
    int4   ca = c4[tid], cb = c4[tid + 512];
    float se[8] = {sa.x, sa.y, sa.z, sa.w, sb.x, sb.y, sb.z, sb.w};
    float ce[8] = {(float)ca.x, (float)ca.y, (float)ca.z, (float)ca.w,
                   (float)cb.x, (float)cb.y, (float)cb.z, (float)cb.w};

    // ---- wave threshold: 32nd-largest of the wave's 64 thread-maxima ----
    float tmax = se[0];
#pragma unroll
    for (int e = 1; e < 8; ++e) tmax = fmaxf(tmax, se[e]);
    float srt = sort64_asc(tmax, lane);
    float t_w = __shfl(srt, 32, 64);
    if (lane == 0) twbuf[wv] = t_w;
    __syncthreads();
    float t = twbuf[0];
#pragma unroll
    for (int w = 1; w < 8; ++w) t = fmaxf(t, twbuf[w]);

    // ---- ballot-compact survivors (>= t); half's true top-32 is a subset ----
    unsigned long long m[8];
    unsigned tot = 0;
#pragma unroll
    for (int e = 0; e < 8; ++e) {
        m[e] = __ballot(se[e] >= t);
        tot += (unsigned)__popcll(m[e]);
    }
    unsigned wbase = 0;
    if (lane == 0) wbase = atomicAdd(&cnt, tot);
    wbase = __shfl(wbase, 0, 64);
    const unsigned long long ltm = (1ull << lane) - 1ull;
#pragma unroll
    for (int e = 0; e < 8; ++e) {
        if (se[e] >= t) {
            unsigned idx = wbase + (unsigned)__popcll(m[e] & ltm);
            if (idx < CAND) cand[idx] = se[e];   // ~280 expected of 4096
        }
        wbase += (unsigned)__popcll(m[e]);
    }
    __syncthreads();

    // ---- top-32 of 512 candidates: 16 group-sorts + 4-round LDS tree ----
    float run = sort32_asc(cand[tid], l);
#pragma unroll
    for (int stride = 1; stride < 16; stride <<= 1) {
        topbuf[h * 32 + l] = run;
        __syncthreads();
        if ((h & (2 * stride - 1)) == 0) {
            float pv = topbuf[(h + stride) * 32 + (l ^ 31)];
            run = merge_asc32(fmaxf(run, pv), l);
        }
        __syncthreads();
    }
    if (tid < 32) mytop[l] = run;
    __syncthreads();

    // ---- separable exp with LOCAL split point y0_local <= y0_global ----
    const float y0 = mytop[0];
    float P = 0.f, Pc = 0.f;
#pragma unroll
    for (int e = 0; e < 8; ++e) {
        if (se[e] <= y0) {
            float ex = fast_exp2(C1 * se[e]);
            P += ex;
            Pc = fmaf(ce[e], ex, Pc);
        } else {                             // strictly > half's 32nd-largest: <=31
            unsigned idx = atomicAdd(&dcnt, 1u);
            dsS[idx] = se[e];
            dsC[idx] = ce[e];
        }
    }
#pragma unroll
    for (int off = 32; off > 0; off >>= 1) {
        P  += __shfl_xor(P,  off, 64);
        Pc += __shfl_xor(Pc, off, 64);
    }
    if (lane == 0) { pbuf[wv * 2] = P; pbuf[wv * 2 + 1] = Pc; }
    __syncthreads();
    float Pt = 0.f, Pct = 0.f;
#pragma unroll
    for (int w = 0; w < 8; ++w) { Pt += pbuf[w * 2]; Pct += pbuf[w * 2 + 1]; }

    unsigned* flags = (unsigned*)(ws + FLAG_FOFF);

    if (half == 1) {
        // ---- post record [top32 | P | Pc | dS[31] | dC[31]] and exit ----
        float* my = ws + (size_t)blk * REC_STRIDE;
        if (tid < 32) my[tid] = mytop[tid];
        if (tid == 0) { my[32] = Pt; my[33] = Pct; }
        if (tid < 31) { my[34 + tid] = dsS[tid]; my[65 + tid] = dsC[tid]; }
        __threadfence();
        __syncthreads();
        if (tid == 0)
            __hip_atomic_store(&flags[blk], MAGIC, __ATOMIC_RELEASE,
                               __HIP_MEMORY_SCOPE_AGENT);
        return;
    }

    // ---- even block: wait for partner, combine ----
    if (tid == 0) {
        while (__hip_atomic_load(&flags[blk + 1], __ATOMIC_ACQUIRE,
                                 __HIP_MEMORY_SCOPE_AGENT) != MAGIC)
            __builtin_amdgcn_s_sleep(4);
    }
    __syncthreads();
    const float* pr = ws + (size_t)(blk + 1) * REC_STRIDE;
    if (tid < 31) {
        dsS[31 + tid] = __hip_atomic_load(&pr[34 + tid], __ATOMIC_RELAXED,
                                          __HIP_MEMORY_SCOPE_AGENT);
        dsC[31 + tid] = __hip_atomic_load(&pr[65 + tid], __ATOMIC_RELAXED,
                                          __HIP_MEMORY_SCOPE_AGENT);
    }
    Pt  += __hip_atomic_load(&pr[32], __ATOMIC_RELAXED, __HIP_MEMORY_SCOPE_AGENT);
    Pct += __hip_atomic_load(&pr[33], __ATOMIC_RELAXED, __HIP_MEMORY_SCOPE_AGENT);

    // merge the two half-top-32 lists (all groups execute; group 0's result used)
    {
        float a = mytop[l];
        float p = __hip_atomic_load(&pr[l], __ATOMIC_RELAXED,
                                    __HIP_MEMORY_SCOPE_AGENT);
        float yk = merge_top32(a, p, l);
        if (tid < 32) {
            yk_lds[l] = yk;
            out[(size_t)row * K_TOP + l] = yk;       // output 0: yk
        }
    }
    __syncthreads();

    // ---- wave wv owns j = 4wv .. 4wv+3 over the <=62 direct entries ----
    const float yj0 = yk_lds[wv * 4 + 0];
    const float yj1 = yk_lds[wv * 4 + 1];
    const float yj2 = yk_lds[wv * 4 + 2];
    const float yj3 = yk_lds[wv * 4 + 3];
    float n0 = 0.f, d0 = 0.f, n1 = 0.f, d1 = 0.f;
    float n2 = 0.f, d2 = 0.f, n3 = 0.f, d3 = 0.f;
    if (lane < 62) {
        float s = dsS[lane], c = dsC[lane];   // padded entries: exp2(-inf)=0
        float e0 = fast_exp2(-C1 * fabsf(s - yj0));
        float e1 = fast_exp2(-C1 * fabsf(s - yj1));
        float e2 = fast_exp2(-C1 * fabsf(s - yj2));
        float e3 = fast_exp2(-C1 * fabsf(s - yj3));
        d0 = e0; n0 = c * e0;  d1 = e1; n1 = c * e1;
        d2 = e2; n2 = c * e2;  d3 = e3; n3 = c * e3;
    }
#pragma unroll
    for (int off = 32; off > 0; off >>= 1) {
        n0 += __shfl_xor(n0, off, 64); d0 += __shfl_xor(d0, off, 64);
        n1 += __shfl_xor(n1, off, 64); d1 += __shfl_xor(d1, off, 64);
        n2 += __shfl_xor(n2, off, 64); d2 += __shfl_xor(d2, off, 64);
        n3 += __shfl_xor(n3, off, 64); d3 += __shfl_xor(d3, off, 64);
    }
    if (lane == 0) {
        float e0 = fast_exp2(-C1 * yj0);
        float e1 = fast_exp2(-C1 * yj1);
        float e2 = fast_exp2(-C1 * yj2);
        float e3 = fast_exp2(-C1 * yj3);
        float* dst = out + (size_t)B * K_TOP + (size_t)row * K_TOP + 4 * wv;
        dst[0] = fmaf(Pct, e0, n0) / fmaf(Pt, e0, d0);
        dst[1] = fmaf(Pct, e1, n1) / fmaf(Pt, e1, d1);
        dst[2] = fmaf(Pct, e2, n2) / fmaf(Pt, e2, d2);
        dst[3] = fmaf(Pct, e3, n3) / fmaf(Pt, e3, d3);
    }
}

extern "C" void kernel_launch(void* const* d_in, const int* in_sizes, int n_in,
                              void* d_out, int out_size, void* d_ws, size_t ws_size,
                              hipStream_t stream) {
    const float* scores = (const float*)d_in[0];
    const int*   rc     = (const int*)d_in[1];
    const int R = in_sizes[1];          // 8192
    const int B = in_sizes[0] / R;      // 128
    float* out = (float*)d_out;
    float* ws  = (float*)d_ws;

    hipLaunchKernelGGL(k_half, dim3(B * 2), dim3(512), 0, stream,
                       scores, rc, out, ws, B);
}

// Round 8
// 66.323 us; speedup vs baseline: 1.5077x; 1.5077x over previous
//
#include <hip/hip_runtime.h>
#include <math.h>

#define R_N    8192
#define K_TOP  32
#define CAND   1024
// 10*log2(e): exp(10*x) = exp2(C1*x)
#define C1     14.426950408889634f
#define NEG_BIG (-3.0e38f)

__device__ __forceinline__ float fast_exp2(float x) {
#if __has_builtin(__builtin_amdgcn_exp2f)
    return __builtin_amdgcn_exp2f(x);
#else
    return exp2f(x);
#endif
}

// ---- bitonic helpers (l = tid & 31 unless noted) ----
__device__ __forceinline__ float merge_asc32(float v, int l) {
#pragma unroll
    for (int j = 16; j > 0; j >>= 1) {
        float pv = __shfl_xor(v, j, 64);
        v = ((l & j) == 0) ? fminf(v, pv) : fmaxf(v, pv);
    }
    return v;
}

__device__ __forceinline__ float sort32_asc(float v, int l) {
#pragma unroll
    for (int k = 2; k <= 32; k <<= 1) {
#pragma unroll
        for (int j = k >> 1; j > 0; j >>= 1) {
            float pv = __shfl_xor(v, j, 64);
            bool keep_min = (((l & k) == 0) == ((l & j) == 0));
            v = keep_min ? fminf(v, pv) : fmaxf(v, pv);
        }
    }
    return v;
}

// full-wave (64-lane) ascending bitonic sort
__device__ __forceinline__ float sort64_asc(float v, int lane) {
#pragma unroll
    for (int k = 2; k <= 64; k <<= 1) {
#pragma unroll
        for (int j = k >> 1; j > 0; j >>= 1) {
            float pv = __shfl_xor(v, j, 64);
            bool keep_min = (((lane & k) == 0) == ((lane & j) == 0));
            v = keep_min ? fminf(v, pv) : fmaxf(v, pv);
        }
    }
    return v;
}

// ===== Fused kernel: one block per row =====
// Phase 1: threshold-prefiltered exact top-32.
// Phase 2: separable-exp softmax expectation from registers (exact).
// NOTE (R7 lesson): no inter-block communication — cross-XCD release/acquire
// flag handshakes cost ~40 us on gfx950 (per-XCD L2 non-coherence).
extern "C" __global__ void __launch_bounds__(1024)
k_fused(const float* __restrict__ scores, const int* __restrict__ rc,
        float* __restrict__ out, int B) {
    __shared__ float    cand[CAND];      // 4 KB survivor scores
    __shared__ float    topbuf[32 * 32]; // 4 KB merge tree
    __shared__ float    twbuf[16];
    __shared__ float    yk_lds[K_TOP];
    __shared__ float    pbuf[16 * 2];
    __shared__ float    dsS[32], dsC[32]; // elements strictly > y0: at most 31
    __shared__ unsigned cnt, dcnt;

    const int row  = blockIdx.x;
    const int tid  = threadIdx.x;
    const int lane = tid & 63;
    const int l    = tid & 31;
    const int h    = tid >> 5;           // 32-group id (0..31)
    const int wv   = tid >> 6;           // wave id (0..15)

    // ---- load 8 scores + 8 classes per thread; hold in registers ----
    const float4* s4 = (const float4*)(scores + (size_t)row * R_N);
    const int4*   c4 = (const int4*)rc;
    float4 sa = s4[tid], sb = s4[tid + 1024];
    int4   ca = c4[tid], cb = c4[tid + 1024];
    float se[8] = {sa.x, sa.y, sa.z, sa.w, sb.x, sb.y, sb.z, sb.w};
    float ce[8] = {(float)ca.x, (float)ca.y, (float)ca.z, (float)ca.w,
                   (float)cb.x, (float)cb.y, (float)cb.z, (float)cb.w};

    cand[tid & (CAND - 1)] = NEG_BIG;    // CAND == blockDim
    if (tid == 0) { cnt = 0; dcnt = 0; }

    // ---- wave threshold: 32nd-largest of the wave's 64 thread-maxima ----
    // The achieving wave proves >=32 elements >= t, so true top-32 survives.
    float tmax = se[0];
#pragma unroll
    for (int e = 1; e < 8; ++e) tmax = fmaxf(tmax, se[e]);
    float srt = sort64_asc(tmax, lane);
    float t_w = __shfl(srt, 32, 64);
    if (lane == 0) twbuf[wv] = t_w;
    __syncthreads();
    float t = twbuf[0];
#pragma unroll
    for (int w = 1; w < 16; ++w) t = fmaxf(t, twbuf[w]);

    // ---- ballot-compact survivors into cand ----
    unsigned long long m[8];
    unsigned tot = 0;
#pragma unroll
    for (int e = 0; e < 8; ++e) {
        m[e] = __ballot(se[e] >= t);
        tot += (unsigned)__popcll(m[e]);
    }
    unsigned wbase = 0;
    if (lane == 0) wbase = atomicAdd(&cnt, tot);
    wbase = __shfl(wbase, 0, 64);
    const unsigned long long ltm = (1ull << lane) - 1ull;
#pragma unroll
    for (int e = 0; e < 8; ++e) {
        if (se[e] >= t) {
            unsigned idx = wbase + (unsigned)__popcll(m[e] & ltm);
            if (idx < CAND) cand[idx] = se[e];  // ~475 expected of 8192
        }
        wbase += (unsigned)__popcll(m[e]);
    }
    __syncthreads();

    // ---- top-32 of 1024 candidates: 32 group-sorts + 5-round LDS tree ----
    float run = sort32_asc(cand[tid], l);
#pragma unroll
    for (int stride = 1; stride < 32; stride <<= 1) {
        topbuf[h * 32 + l] = run;
        __syncthreads();
        if ((h & (2 * stride - 1)) == 0) {
            float pv = topbuf[(h + stride) * 32 + (l ^ 31)];
            run = merge_asc32(fmaxf(run, pv), l);
        }
        __syncthreads();
    }
    if (tid < 32) {
        yk_lds[l] = run;
        out[(size_t)row * K_TOP + l] = run;     // output 0: yk
    }
    __syncthreads();
    const float y0 = yk_lds[0];

    // ---- separable exp: s <= y0 <= y_j => exp(-10|s-y_j|) = e^{-10 y_j} e^{10 s}
    float P = 0.f, Pc = 0.f;
#pragma unroll
    for (int e = 0; e < 8; ++e) {
        if (se[e] <= y0) {
            float ex = fast_exp2(C1 * se[e]);
            P += ex;
            Pc = fmaf(ce[e], ex, Pc);
        } else {                                 // at most 31 of these per row
            unsigned idx = atomicAdd(&dcnt, 1u);
            dsS[idx] = se[e];
            dsC[idx] = ce[e];
        }
    }
#pragma unroll
    for (int off = 32; off > 0; off >>= 1) {
        P  += __shfl_xor(P,  off, 64);
        Pc += __shfl_xor(Pc, off, 64);
    }
    if (lane == 0) { pbuf[wv * 2] = P; pbuf[wv * 2 + 1] = Pc; }
    __syncthreads();
    float Pt = 0.f, Pct = 0.f;
#pragma unroll
    for (int w = 0; w < 16; ++w) { Pt += pbuf[w * 2]; Pct += pbuf[w * 2 + 1]; }
    const int nD = (int)dcnt;

    // ---- wave wv owns j = 2wv, 2wv+1 ----
    const float yj0 = yk_lds[2 * wv];
    const float yj1 = yk_lds[2 * wv + 1];
    float n0 = 0.f, d0 = 0.f, n1 = 0.f, d1 = 0.f;
    if (lane < nD) {
        float s = dsS[lane], c = dsC[lane];
        float e0 = fast_exp2(-C1 * fabsf(s - yj0));
        float e1 = fast_exp2(-C1 * fabsf(s - yj1));
        d0 = e0; n0 = c * e0;
        d1 = e1; n1 = c * e1;
    }
#pragma unroll
    for (int off = 32; off > 0; off >>= 1) {
        n0 += __shfl_xor(n0, off, 64); d0 += __shfl_xor(d0, off, 64);
        n1 += __shfl_xor(n1, off, 64); d1 += __shfl_xor(d1, off, 64);
    }
    if (lane == 0) {
        float e0 = fast_exp2(-C1 * yj0);
        float e1 = fast_exp2(-C1 * yj1);
        float* dst = out + (size_t)B * K_TOP + (size_t)row * K_TOP + 2 * wv;
        dst[0] = fmaf(Pct, e0, n0) / fmaf(Pt, e0, d0);
        dst[1] = fmaf(Pct, e1, n1) / fmaf(Pt, e1, d1);
    }
}

extern "C" void kernel_launch(void* const* d_in, const int* in_sizes, int n_in,
                              void* d_out, int out_size, void* d_ws, size_t ws_size,
                              hipStream_t stream) {
    const float* scores = (const float*)d_in[0];
    const int*   rc     = (const int*)d_in[1];
    const int R = in_sizes[1];          // 8192
    const int B = in_sizes[0] / R;      // 128
    float* out = (float*)d_out;

    hipLaunchKernelGGL(k_fused, dim3(B), dim3(1024), 0, stream, scores, rc, out, B);
}